// Round 2
// baseline (761.906 us; speedup 1.0000x reference)
//
#include <hip/hip_runtime.h>
#include <stdint.h>

#define B_SZ   8192
#define IN_DIM 512
#define HID    256
#define PROJ   128

typedef __attribute__((ext_vector_type(8))) short bf16x8;
typedef __attribute__((ext_vector_type(4))) float f32x4;

#define GLDS16(gp, lp) __builtin_amdgcn_global_load_lds( \
    (const __attribute__((address_space(1))) void*)(gp), \
    (__attribute__((address_space(3))) void*)(lp), 16, 0, 0)

__device__ __forceinline__ unsigned short f2bf(float f) {
    union { float f; uint32_t u; } c; c.f = f;
    uint32_t u = c.u;
    uint32_t r = (u + 0x7fffu + ((u >> 16) & 1u)) >> 16;   // RNE
    return (unsigned short)r;
}

// ------- K0: convert W2 to bf16 (no x-transpose needed anymore) ----------
__global__ __launch_bounds__(256) void k0_prep(
        const float4* __restrict__ W2, ushort4* __restrict__ W2b) {
    const int nW2 = (PROJ * IN_DIM * HID) / 4;
    const int stride = 2048 * 256;
    for (int i = blockIdx.x * 256 + threadIdx.x; i < nW2; i += stride) {
        float4 v = W2[i];
        ushort4 o;
        o.x = f2bf(v.x); o.y = f2bf(v.y); o.z = f2bf(v.z); o.w = f2bf(v.w);
        W2b[i] = o;
    }
}

// ---------------- shared: f32 -> bf16x8 load helper ----------------------
__device__ __forceinline__ bf16x8 ld_cvt8(const float* __restrict__ s) {
    float4 a = *(const float4*)s;
    float4 b = *(const float4*)(s + 4);
    bf16x8 r;
    r[0] = (short)f2bf(a.x); r[1] = (short)f2bf(a.y);
    r[2] = (short)f2bf(a.z); r[3] = (short)f2bf(a.w);
    r[4] = (short)f2bf(b.x); r[5] = (short)f2bf(b.y);
    r[6] = (short)f2bf(b.z); r[7] = (short)f2bf(b.w);
    return r;
}

// ---------------- K1: h = relu(ft @ W1^T + b1), bf16 out -----------------
__global__ __launch_bounds__(256) void k1_hidden(
        const float* __restrict__ ft,
        const float* __restrict__ W1,
        const float* __restrict__ b1,
        unsigned short* __restrict__ hb) {
    const int lane = threadIdx.x & 63;
    const int wv   = threadIdx.x >> 6;
    const int l15  = lane & 15, q = lane >> 4;
    const int b0 = blockIdx.x * 32;
    const int n0 = wv * 64;

    f32x4 acc[2][4];
    const f32x4 z4 = {0.f, 0.f, 0.f, 0.f};
    #pragma unroll
    for (int mt = 0; mt < 2; ++mt)
        #pragma unroll
        for (int nt = 0; nt < 4; ++nt) acc[mt][nt] = z4;

    for (int kq = 0; kq < 16; ++kq) {
        const int koff = kq * 32 + q * 8;
        bf16x8 a[2], bb[4];
        #pragma unroll
        for (int mt = 0; mt < 2; ++mt)
            a[mt] = ld_cvt8(ft + (size_t)(b0 + mt*16 + l15) * IN_DIM + koff);
        #pragma unroll
        for (int nt = 0; nt < 4; ++nt)
            bb[nt] = ld_cvt8(W1 + (size_t)(n0 + nt*16 + l15) * IN_DIM + koff);
        #pragma unroll
        for (int mt = 0; mt < 2; ++mt)
            #pragma unroll
            for (int nt = 0; nt < 4; ++nt)
                acc[mt][nt] = __builtin_amdgcn_mfma_f32_16x16x32_bf16(
                    a[mt], bb[nt], acc[mt][nt], 0, 0, 0);
    }
    #pragma unroll
    for (int nt = 0; nt < 4; ++nt) {
        float bias = b1[n0 + nt*16 + l15];
        #pragma unroll
        for (int mt = 0; mt < 2; ++mt)
            #pragma unroll
            for (int r = 0; r < 4; ++r) {
                float v = acc[mt][nt][r] + bias;
                v = fmaxf(v, 0.f);
                hb[(size_t)(b0 + mt*16 + q*4 + r) * HID + n0 + nt*16 + l15] = f2bf(v);
            }
    }
}

// ---------------- K2: outT[p,b] = sum_i x[b,i] * b2[p*512+i] -------------
// Bias term of the fused einsum, written TRANSPOSED (outT[p][b]) so both
// k2's stores and k3's += are coalesced full-64B segments (R1's scattered
// 4B RMW caused 84MB write amplification). A = b2 (rows=p), B = x (cols=b).
__global__ __launch_bounds__(256) void k2_bias(
        const float* __restrict__ x,
        const float* __restrict__ b2,
        float* __restrict__ outT) {
    const int lane = threadIdx.x & 63;
    const int wv   = threadIdx.x >> 6;
    const int l15  = lane & 15, q = lane >> 4;
    const int b0 = blockIdx.x * 64;      // grid 128
    const int pw = wv * 32;

    f32x4 acc[2][4];
    const f32x4 z4 = {0.f, 0.f, 0.f, 0.f};
    #pragma unroll
    for (int pt = 0; pt < 2; ++pt)
        #pragma unroll
        for (int bb = 0; bb < 4; ++bb) acc[pt][bb] = z4;

    for (int kq = 0; kq < 16; ++kq) {
        const int koff = kq * 32 + q * 8;
        bf16x8 a[2], bx[4];
        #pragma unroll
        for (int pt = 0; pt < 2; ++pt)
            a[pt] = ld_cvt8(b2 + (size_t)(pw + pt*16 + l15) * IN_DIM + koff);
        #pragma unroll
        for (int bb = 0; bb < 4; ++bb)
            bx[bb] = ld_cvt8(x + (size_t)(b0 + bb*16 + l15) * IN_DIM + koff);
        #pragma unroll
        for (int pt = 0; pt < 2; ++pt)
            #pragma unroll
            for (int bb = 0; bb < 4; ++bb)
                acc[pt][bb] = __builtin_amdgcn_mfma_f32_16x16x32_bf16(
                    a[pt], bx[bb], acc[pt][bb], 0, 0, 0);
    }
    // D: row = p-offset (q*4+r), col = b-offset (l15)
    #pragma unroll
    for (int pt = 0; pt < 2; ++pt)
        #pragma unroll
        for (int bb = 0; bb < 4; ++bb)
            #pragma unroll
            for (int r = 0; r < 4; ++r)
                outT[(size_t)(pw + pt*16 + q*4 + r) * B_SZ + b0 + bb*16 + l15]
                    = acc[pt][bb][r];
}

// ---------------- K3: outT[p,b] += sum_i x[b,i]*(sum_k h[b,k]*W2[p,i,k]) --
// SWAPPED MFMA operands: D = mfma(A=W2frag, B=hfrag) puts b on the D COLUMN
// (lane-fixed) and i on the D rows (reg-indexed). The x-contraction then
// needs ONE scalar acc per (pp,bt) + one contiguous float4 of untransposed
// x — this is what makes bt=8 h-tile reuse fit in registers (~150 VGPR at
// (256,3); R1's unswapped mt=4 needed ~190 and spilled: WRITE_SIZE 84MB).
// Per wave-step: 64 MFMA vs 8KB LDS (8x B-reuse) vs ~128 fmaf — balanced.
__global__ __launch_bounds__(256, 3) void k3_main(
        const unsigned short* __restrict__ W2b,
        const unsigned short* __restrict__ hb,
        const float* __restrict__ x,
        float* __restrict__ outT) {
    __shared__ unsigned short lbs[2][64 * 64];   // 2 x 8 KB: [row=(p,i) 64][k 64]
    const int tid  = threadIdx.x;
    const int lane = tid & 63;
    const int wv   = tid >> 6;
    const int l15  = lane & 15, q = lane >> 4;
    const int pgrp = blockIdx.x & 63;            // stride-64 => same XCD per p-pair
    const int bsup = blockIdx.x >> 6;            // 0..15
    const int p0   = pgrp * 2;
    const int b0w  = bsup * 512 + wv * 128;      // 128 b-rows per wave (bt=8)
    const f32x4 z4 = {0.f, 0.f, 0.f, 0.f};

    // glds writer mapping: inst jj covers tile rows wv*16+jj*8 .. +7;
    // lane -> (row = base+lane>>3, chunkpos = lane&7); swizzle on SOURCE:
    // chunkpos holds global 16B-chunk c = chunkpos ^ (row&7).
    const int grow = lane >> 3;
    const int gchk = lane & 7;

    const unsigned short* gsrc[2];
    #pragma unroll
    for (int jj = 0; jj < 2; ++jj) {
        const int r = wv*16 + jj*8 + grow;       // tile row: p=(r>>5), i_local=(r&31)
        const int c = gchk ^ (r & 7);            // pre-swizzled source chunk
        gsrc[jj] = W2b + ((size_t)(p0 + (r >> 5)) * IN_DIM + (r & 31)) * HID + c * 8;
    }

    float oacc[2][8];
    #pragma unroll
    for (int pp = 0; pp < 2; ++pp)
        #pragma unroll
        for (int bt = 0; bt < 8; ++bt) oacc[pp][bt] = 0.f;

    bf16x8 afr[8][2];   // h fragments (B-operand): bt=8 tiles x kq=2, K-chunk 64

    const unsigned short* hbase = hb + (size_t)(b0w + l15) * HID + q * 8;
    const float* xbase = x + (size_t)(b0w + l15) * IN_DIM + q * 4;

    // ---- prologue: issue tile 0 (kh=0, ic=0) ----
    #pragma unroll
    for (int jj = 0; jj < 2; ++jj)
        GLDS16(gsrc[jj], &lbs[0][(wv*16 + jj*8) * 64]);

    #pragma unroll 1
    for (int t = 0; t < 64; ++t) {
        __syncthreads();   // drains tile-t glds; all waves done with buf[(t-1)&1]

        if (t < 63) {      // prefetch t+1 into the buffer just released
            const int tn = t + 1;
            const int khn = tn >> 4, icn = tn & 15;
            unsigned short* Ld = lbs[tn & 1];
            #pragma unroll
            for (int jj = 0; jj < 2; ++jj)
                GLDS16(gsrc[jj] + (size_t)icn * 32 * HID + khn * 64,
                       &Ld[(wv*16 + jj*8) * 64]);
        }

        const int kh = t >> 4;
        const int ic = t & 15;
        if ((t & 15) == 0) {   // load h fragments for this K-chunk of 64
            #pragma unroll
            for (int bt = 0; bt < 8; ++bt) {
                const unsigned short* hrow = hbase + bt * 16 * HID + kh * 64;
                afr[bt][0] = *(const bf16x8*)(hrow);
                afr[bt][1] = *(const bf16x8*)(hrow + 32);
            }
        }

        const unsigned short* Lb = lbs[t & 1];

        #pragma unroll
        for (int sub = 0; sub < 2; ++sub) {
            // x[b, i] for i = ic*32 + sub*16 + q*4 + r  (contiguous float4)
            float4 xq[8];
            #pragma unroll
            for (int bt = 0; bt < 8; ++bt)
                xq[bt] = *(const float4*)(xbase + (size_t)bt * 16 * IN_DIM
                                          + ic * 32 + sub * 16);
            #pragma unroll
            for (int pp = 0; pp < 2; ++pp) {
                const int trow = pp*32 + sub*16 + l15;
                const int sw = trow & 7;
                bf16x8 wf0 = *(const bf16x8*)(&Lb[trow*64 + ((q)     ^ sw) * 8]);
                bf16x8 wf1 = *(const bf16x8*)(&Lb[trow*64 + ((4 + q) ^ sw) * 8]);
                #pragma unroll
                for (int bt = 0; bt < 8; ++bt) {
                    f32x4 D = __builtin_amdgcn_mfma_f32_16x16x32_bf16(
                        wf0, afr[bt][0], z4, 0, 0, 0);
                    D = __builtin_amdgcn_mfma_f32_16x16x32_bf16(
                        wf1, afr[bt][1], D, 0, 0, 0);
                    // D: row=i-offset (q*4+r), col=b (l15) -> dot with x
                    float v = oacc[pp][bt];
                    v = fmaf(D[0], xq[bt].x, v);
                    v = fmaf(D[1], xq[bt].y, v);
                    v = fmaf(D[2], xq[bt].z, v);
                    v = fmaf(D[3], xq[bt].w, v);
                    oacc[pp][bt] = v;
                }
            }
        }
    }

    // ---- epilogue: reduce over the 4 q-groups (i-quads), store coalesced ----
    #pragma unroll
    for (int pp = 0; pp < 2; ++pp)
        #pragma unroll
        for (int bt = 0; bt < 8; ++bt) {
            float v = oacc[pp][bt];
            v += __shfl_xor(v, 16, 64);
            v += __shfl_xor(v, 32, 64);
            if (lane < 16)
                outT[(size_t)(p0 + pp) * B_SZ + b0w + bt*16 + lane] += v;
        }
}

// ---------------- K4: transpose outT[128][8192] -> out[8192][128] --------
__global__ __launch_bounds__(256) void k4_tr(
        const float* __restrict__ outT, float* __restrict__ out) {
    __shared__ float tile[64][65];
    const int pb = blockIdx.x & 1;
    const int bb = blockIdx.x >> 1;
    const int p0 = pb * 64, b0 = bb * 64;
    const int t = threadIdx.x;
    const int c = t & 63, r4 = t >> 6;
    #pragma unroll
    for (int rr = 0; rr < 64; rr += 4)
        tile[rr + r4][c] = outT[(size_t)(p0 + rr + r4) * B_SZ + b0 + c];
    __syncthreads();
    #pragma unroll
    for (int rr = 0; rr < 64; rr += 4)
        out[(size_t)(b0 + rr + r4) * PROJ + p0 + c] = tile[c][rr + r4];
}

extern "C" void kernel_launch(void* const* d_in, const int* in_sizes, int n_in,
                              void* d_out, int out_size, void* d_ws, size_t ws_size,
                              hipStream_t stream) {
    const float* ft = (const float*)d_in[0];
    const float* x  = (const float*)d_in[1];
    const float* W1 = (const float*)d_in[2];
    const float* b1 = (const float*)d_in[3];
    const float* W2 = (const float*)d_in[4];
    const float* b2 = (const float*)d_in[5];
    float* out = (float*)d_out;

    char* ws = (char*)d_ws;
    unsigned short* W2b = (unsigned short*)(ws);             // 33,554,432 B
    unsigned short* hb  = (unsigned short*)(ws + 33554432);  //  4,194,304 B
    float*          oT  = (float*)(ws + 37748736);           //  4,194,304 B

    hipLaunchKernelGGL(k0_prep, dim3(2048), dim3(256), 0, stream,
        (const float4*)W2, (ushort4*)W2b);
    hipLaunchKernelGGL(k1_hidden, dim3(256), dim3(256), 0, stream, ft, W1, b1, hb);
    hipLaunchKernelGGL(k2_bias, dim3(128), dim3(256), 0, stream, x, b2, oT);
    hipLaunchKernelGGL(k3_main, dim3(1024), dim3(256), 0, stream, W2b, hb, x, oT);
    hipLaunchKernelGGL(k4_tr, dim3(256), dim3(256), 0, stream, oT, out);
}

// Round 4
// 462.043 us; speedup vs baseline: 1.6490x; 1.6490x over previous
//
#include <hip/hip_runtime.h>
#include <stdint.h>

#define B_SZ   8192
#define IN_DIM 512
#define HID    256
#define PROJ   128

typedef __attribute__((ext_vector_type(8))) short bf16x8;
typedef __attribute__((ext_vector_type(4))) float f32x4;

#define GLDS16(gp, lp) __builtin_amdgcn_global_load_lds( \
    (const __attribute__((address_space(1))) void*)(gp), \
    (__attribute__((address_space(3))) void*)(lp), 16, 0, 0)

__device__ __forceinline__ unsigned short f2bf(float f) {
    union { float f; uint32_t u; } c; c.f = f;
    uint32_t u = c.u;
    uint32_t r = (u + 0x7fffu + ((u >> 16) & 1u)) >> 16;   // RNE
    return (unsigned short)r;
}
__device__ __forceinline__ float bfhi(uint32_t v) {
    union { uint32_t u; float f; } c; c.u = v & 0xffff0000u; return c.f;
}
__device__ __forceinline__ float bflo(uint32_t v) {
    union { uint32_t u; float f; } c; c.u = v << 16; return c.f;
}

// ------- K0: convert W2 to bf16 (blocks 0..2047) + transpose x to bf16 ----
__global__ __launch_bounds__(256) void k0_prep(
        const float4* __restrict__ W2, ushort4* __restrict__ W2b,
        const float* __restrict__ x, unsigned short* __restrict__ xTb) {
    __shared__ float tile[64][65];
    const int bid = blockIdx.x;
    if (bid < 2048) {
        const int nW2 = (PROJ * IN_DIM * HID) / 4;
        const int stride = 2048 * 256;
        for (int i = bid * 256 + threadIdx.x; i < nW2; i += stride) {
            float4 v = W2[i];
            ushort4 o;
            o.x = f2bf(v.x); o.y = f2bf(v.y); o.z = f2bf(v.z); o.w = f2bf(v.w);
            W2b[i] = o;
        }
    } else {
        const int tb = bid - 2048;
        const int bi = tb & 7, bb = tb >> 3;
        const int i0 = bi * 64, b0 = bb * 64;
        const int t = threadIdx.x;
        const int c = t & 63, r4 = t >> 6;
        #pragma unroll
        for (int rr = 0; rr < 64; rr += 4)
            tile[rr + r4][c] = x[(size_t)(b0 + rr + r4) * IN_DIM + i0 + c];
        __syncthreads();
        #pragma unroll
        for (int rr = 0; rr < 64; rr += 4)
            xTb[(size_t)(i0 + rr + r4) * B_SZ + b0 + c] = f2bf(tile[c][rr + r4]);
    }
}

// ---------------- shared: f32 -> bf16x8 load helper ----------------------
__device__ __forceinline__ bf16x8 ld_cvt8(const float* __restrict__ s) {
    float4 a = *(const float4*)s;
    float4 b = *(const float4*)(s + 4);
    bf16x8 r;
    r[0] = (short)f2bf(a.x); r[1] = (short)f2bf(a.y);
    r[2] = (short)f2bf(a.z); r[3] = (short)f2bf(a.w);
    r[4] = (short)f2bf(b.x); r[5] = (short)f2bf(b.y);
    r[6] = (short)f2bf(b.z); r[7] = (short)f2bf(b.w);
    return r;
}

// ---------------- K1: h = relu(ft @ W1^T + b1), bf16 out -----------------
__global__ __launch_bounds__(256) void k1_hidden(
        const float* __restrict__ ft,
        const float* __restrict__ W1,
        const float* __restrict__ b1,
        unsigned short* __restrict__ hb) {
    const int lane = threadIdx.x & 63;
    const int wv   = threadIdx.x >> 6;
    const int l15  = lane & 15, q = lane >> 4;
    const int b0 = blockIdx.x * 32;
    const int n0 = wv * 64;

    f32x4 acc[2][4];
    const f32x4 z4 = {0.f, 0.f, 0.f, 0.f};
    #pragma unroll
    for (int mt = 0; mt < 2; ++mt)
        #pragma unroll
        for (int nt = 0; nt < 4; ++nt) acc[mt][nt] = z4;

    for (int kq = 0; kq < 16; ++kq) {
        const int koff = kq * 32 + q * 8;
        bf16x8 a[2], bb[4];
        #pragma unroll
        for (int mt = 0; mt < 2; ++mt)
            a[mt] = ld_cvt8(ft + (size_t)(b0 + mt*16 + l15) * IN_DIM + koff);
        #pragma unroll
        for (int nt = 0; nt < 4; ++nt)
            bb[nt] = ld_cvt8(W1 + (size_t)(n0 + nt*16 + l15) * IN_DIM + koff);
        #pragma unroll
        for (int mt = 0; mt < 2; ++mt)
            #pragma unroll
            for (int nt = 0; nt < 4; ++nt)
                acc[mt][nt] = __builtin_amdgcn_mfma_f32_16x16x32_bf16(
                    a[mt], bb[nt], acc[mt][nt], 0, 0, 0);
    }
    #pragma unroll
    for (int nt = 0; nt < 4; ++nt) {
        float bias = b1[n0 + nt*16 + l15];
        #pragma unroll
        for (int mt = 0; mt < 2; ++mt)
            #pragma unroll
            for (int r = 0; r < 4; ++r) {
                float v = acc[mt][nt][r] + bias;
                v = fmaxf(v, 0.f);
                hb[(size_t)(b0 + mt*16 + q*4 + r) * HID + n0 + nt*16 + l15] = f2bf(v);
            }
    }
}

// ---------------- K2: out[b,p] = sum_i x[b,i] * b2[p*512+i] --------------
// Bias term of the fused einsum (verified in R1). k3 does out[] += v.
__global__ __launch_bounds__(256) void k2_bias(
        const float* __restrict__ x,
        const float* __restrict__ b2,
        float* __restrict__ out) {
    const int lane = threadIdx.x & 63;
    const int wv   = threadIdx.x >> 6;
    const int l15  = lane & 15, q = lane >> 4;
    const int b0 = blockIdx.x * 32;
    const int n0 = wv * 32;

    f32x4 acc[2][2];
    const f32x4 z4 = {0.f, 0.f, 0.f, 0.f};
    #pragma unroll
    for (int mt = 0; mt < 2; ++mt)
        #pragma unroll
        for (int nt = 0; nt < 2; ++nt) acc[mt][nt] = z4;

    for (int kq = 0; kq < 16; ++kq) {
        const int koff = kq * 32 + q * 8;
        bf16x8 a[2], bb[2];
        #pragma unroll
        for (int mt = 0; mt < 2; ++mt)
            a[mt] = ld_cvt8(x + (size_t)(b0 + mt*16 + l15) * IN_DIM + koff);
        #pragma unroll
        for (int nt = 0; nt < 2; ++nt)
            bb[nt] = ld_cvt8(b2 + (size_t)(n0 + nt*16 + l15) * IN_DIM + koff);
        #pragma unroll
        for (int mt = 0; mt < 2; ++mt)
            #pragma unroll
            for (int nt = 0; nt < 2; ++nt)
                acc[mt][nt] = __builtin_amdgcn_mfma_f32_16x16x32_bf16(
                    a[mt], bb[nt], acc[mt][nt], 0, 0, 0);
    }
    #pragma unroll
    for (int mt = 0; mt < 2; ++mt)
        #pragma unroll
        for (int nt = 0; nt < 2; ++nt)
            #pragma unroll
            for (int r = 0; r < 4; ++r)
                out[(size_t)(b0 + mt*16 + q*4 + r) * PROJ + n0 + nt*16 + l15]
                    = acc[mt][nt][r];
}

// ---------------- K3: out[b,p] += sum_i x[b,i]*(sum_k h[b,k]*W2[p,i,k]) --
// R0's verified geometry (4 waves x 32 b-rows, p-pair, 16KB W2 step-tile,
// XOR-16B swizzle g = pos^(row&7)) + T3/T4 counted-vmcnt pipeline:
//   - x staged to LDS (8KB/step, same swizzle) -> NO per-lane global loads
//     in the loop (in-order vmcnt would otherwise drain the glds prefetch).
//   - h (full K=256) in registers from prologue; b2 hoisted to k2.
//   - loop: vmcnt(6) [t landed, t+1 in flight] -> barrier -> compute ->
//     barrier -> STAGE(t+2). Never vmcnt(0) mid-loop (the ~20% drain stall
//     of __syncthreads, per m97/m233).
// All ds_read results are consumed before barrier-2 => no lgkm hazard.
__global__ __launch_bounds__(256, 3) void k3_main(
        const unsigned short* __restrict__ W2b,
        const unsigned short* __restrict__ hb,
        const unsigned short* __restrict__ xTb,
        float* __restrict__ out) {
    __shared__ unsigned short w2t[2][64 * 128];   // 2 x 16 KB
    __shared__ unsigned short xt[2][32 * 128];    // 2 x  8 KB
    const int tid  = threadIdx.x;
    const int lane = tid & 63;
    const int wv   = tid >> 6;
    const int l15  = lane & 15, q = lane >> 4;
    const int pgrp = blockIdx.x & 63;             // stride-64 => same XCD per p-pair
    const int bsup = blockIdx.x >> 6;             // 0..63
    const int p0   = pgrp * 2;
    const int b0blk = bsup * 128;
    const int b0w  = b0blk + wv * 32;
    const f32x4 z4 = {0.f, 0.f, 0.f, 0.f};

    // ---- h fragments, full K=256, loaded once (prologue) ----
    bf16x8 afr[2][8];
    #pragma unroll
    for (int mt = 0; mt < 2; ++mt) {
        const unsigned short* hrow = hb + (size_t)(b0w + mt*16 + l15) * HID + q * 8;
        #pragma unroll
        for (int kk = 0; kk < 8; ++kk)
            afr[mt][kk] = *(const bf16x8*)(hrow + kk * 32);
    }

    // ---- glds source pointers (per-lane, pre-swizzled) ----
    const int grow = lane >> 4;
    const int cbase = (lane & 15) ^ grow;
    const unsigned short* wsp[4];
    #pragma unroll
    for (int jj = 0; jj < 4; ++jj) {
        const int j   = wv*4 + jj;
        const int row = j*4 + grow;               // p=(row>>5), i_local=(row&31)
        const int c   = cbase ^ (4*(jj & 1));     // == (lane&15) ^ (row&7)
        wsp[jj] = W2b + ((size_t)(p0 + (row >> 5)) * IN_DIM + (row & 31)) * HID + c * 8;
    }
    const unsigned short* xsp[2];
    #pragma unroll
    for (int jj = 0; jj < 2; ++jj) {
        const int j2  = wv*2 + jj;
        const int row = j2*4 + (lane >> 4);       // i_local 0..31
        const int g   = (lane & 15) ^ (row & 7);  // stored chunk = pos ^ (row&7)
        xsp[jj] = xTb + (size_t)row * B_SZ + b0blk + g * 8;
    }

    float oacc[2][2][4];
    #pragma unroll
    for (int pp = 0; pp < 2; ++pp)
        #pragma unroll
        for (int mt = 0; mt < 2; ++mt)
            #pragma unroll
            for (int r = 0; r < 4; ++r) oacc[pp][mt][r] = 0.f;

#define STAGE(BUFI, TT) do {                                              \
    const int _kh = (TT) >> 4, _ic = (TT) & 15;                           \
    const size_t _wadd = (size_t)(_ic * 32) * HID + _kh * 128;            \
    const size_t _xadd = (size_t)(_ic * 32) * B_SZ;                       \
    unsigned short* _Lw = &w2t[BUFI][0];                                  \
    unsigned short* _Lx = &xt[BUFI][0];                                   \
    _Pragma("unroll")                                                     \
    for (int _jj = 0; _jj < 4; ++_jj)                                     \
        GLDS16(wsp[_jj] + _wadd, _Lw + (wv*4 + _jj) * 512);               \
    _Pragma("unroll")                                                     \
    for (int _jj = 0; _jj < 2; ++_jj)                                     \
        GLDS16(xsp[_jj] + _xadd, _Lx + (wv*2 + _jj) * 512);               \
} while (0)

// KHC must be a literal (static afr indexing, rule #20).
#define COMPUTE(KHC) do {                                                 \
    _Pragma("unroll")                                                     \
    for (int sub = 0; sub < 2; ++sub) {                                   \
        const int rloc = sub*16 + l15;                                    \
        uint2 xv[2];                                                      \
        _Pragma("unroll")                                                 \
        for (int mt = 0; mt < 2; ++mt) {                                  \
            const int gch = wv*4 + mt*2 + (q >> 1);                       \
            const int pos = gch ^ (rloc & 7);                             \
            xv[mt] = *(const uint2*)(Lx + rloc*128 + pos*8 + (q & 1)*4);  \
        }                                                                 \
        _Pragma("unroll")                                                 \
        for (int pp = 0; pp < 2; ++pp) {                                  \
            const unsigned short* Bp = Lw + (pp*32 + rloc) * 128;         \
            const int sw = rloc & 7;                                      \
            bf16x8 bfr[4];                                                \
            _Pragma("unroll")                                             \
            for (int kq = 0; kq < 4; ++kq)                                \
                bfr[kq] = *(const bf16x8*)(Bp + (((q + 4*kq) ^ sw)) * 8); \
            f32x4 D[2];                                                   \
            _Pragma("unroll")                                             \
            for (int mt = 0; mt < 2; ++mt)                                \
                D[mt] = __builtin_amdgcn_mfma_f32_16x16x32_bf16(          \
                    afr[mt][(KHC)*4 + 0], bfr[0], z4, 0, 0, 0);           \
            _Pragma("unroll")                                             \
            for (int kq = 1; kq < 4; ++kq)                                \
                _Pragma("unroll")                                         \
                for (int mt = 0; mt < 2; ++mt)                            \
                    D[mt] = __builtin_amdgcn_mfma_f32_16x16x32_bf16(      \
                        afr[mt][(KHC)*4 + kq], bfr[kq], D[mt], 0, 0, 0);  \
            _Pragma("unroll")                                             \
            for (int mt = 0; mt < 2; ++mt) {                              \
                oacc[pp][mt][0] = fmaf(D[mt][0], bflo(xv[mt].x), oacc[pp][mt][0]); \
                oacc[pp][mt][1] = fmaf(D[mt][1], bfhi(xv[mt].x), oacc[pp][mt][1]); \
                oacc[pp][mt][2] = fmaf(D[mt][2], bflo(xv[mt].y), oacc[pp][mt][2]); \
                oacc[pp][mt][3] = fmaf(D[mt][3], bfhi(xv[mt].y), oacc[pp][mt][3]); \
            }                                                             \
        }                                                                 \
    }                                                                     \
} while (0)

    // ---- prologue: tiles 0 and 1 in flight ----
    STAGE(0, 0);
    STAGE(1, 1);

    #pragma unroll 1
    for (int t = 0; t < 32; ++t) {
        // tile t landed (own 6 oldest); tile t+1 stays in flight
        if (t < 31) asm volatile("s_waitcnt vmcnt(6)" ::: "memory");
        else        asm volatile("s_waitcnt vmcnt(0)" ::: "memory");
        __builtin_amdgcn_s_barrier();     // all waves' tile-t data visible
        asm volatile("" ::: "memory");

        const unsigned short* Lw = &w2t[t & 1][0];
        const unsigned short* Lx = &xt[t & 1][0];
        if (t < 16) COMPUTE(0);
        else        COMPUTE(1);

        asm volatile("" ::: "memory");
        __builtin_amdgcn_s_barrier();     // all waves done reading buf[t&1]
        asm volatile("" ::: "memory");

        if (t < 30) {
            const int tn = t + 2;
            STAGE(tn & 1, tn);            // overwrite the buffer just released
        }
    }
#undef STAGE
#undef COMPUTE

    // ---- epilogue: reduce over 16 i-lanes, accumulate onto k2's bias ----
    #pragma unroll
    for (int pp = 0; pp < 2; ++pp)
        #pragma unroll
        for (int mt = 0; mt < 2; ++mt)
            #pragma unroll
            for (int r = 0; r < 4; ++r) {
                float v = oacc[pp][mt][r];
                v += __shfl_xor(v, 1, 16);
                v += __shfl_xor(v, 2, 16);
                v += __shfl_xor(v, 4, 16);
                v += __shfl_xor(v, 8, 16);
                if (l15 == 0)
                    out[(size_t)(b0w + mt*16 + q*4 + r) * PROJ + p0 + pp] += v;
            }
}

extern "C" void kernel_launch(void* const* d_in, const int* in_sizes, int n_in,
                              void* d_out, int out_size, void* d_ws, size_t ws_size,
                              hipStream_t stream) {
    const float* ft = (const float*)d_in[0];
    const float* x  = (const float*)d_in[1];
    const float* W1 = (const float*)d_in[2];
    const float* b1 = (const float*)d_in[3];
    const float* W2 = (const float*)d_in[4];
    const float* b2 = (const float*)d_in[5];
    float* out = (float*)d_out;

    char* ws = (char*)d_ws;
    unsigned short* W2b = (unsigned short*)(ws);             // 33,554,432 B
    unsigned short* hb  = (unsigned short*)(ws + 33554432);  //  4,194,304 B
    unsigned short* xTb = (unsigned short*)(ws + 37748736);  //  8,388,608 B

    hipLaunchKernelGGL(k0_prep, dim3(3072), dim3(256), 0, stream,
        (const float4*)W2, (ushort4*)W2b, x, xTb);
    hipLaunchKernelGGL(k1_hidden, dim3(256), dim3(256), 0, stream, ft, W1, b1, hb);
    hipLaunchKernelGGL(k2_bias, dim3(256), dim3(256), 0, stream, x, b2, out);
    hipLaunchKernelGGL(k3_main, dim3(4096), dim3(256), 0, stream, W2b, hb, xTb, out);
}

// Round 5
// 455.314 us; speedup vs baseline: 1.6734x; 1.0148x over previous
//
#include <hip/hip_runtime.h>
#include <stdint.h>

#define B_SZ   8192
#define IN_DIM 512
#define HID    256
#define PROJ   128

typedef __attribute__((ext_vector_type(8))) short bf16x8;
typedef __attribute__((ext_vector_type(4))) float f32x4;

#define GLDS16(gp, lp) __builtin_amdgcn_global_load_lds( \
    (const __attribute__((address_space(1))) void*)(gp), \
    (__attribute__((address_space(3))) void*)(lp), 16, 0, 0)

__device__ __forceinline__ unsigned short f2bf(float f) {
    union { float f; uint32_t u; } c; c.f = f;
    uint32_t u = c.u;
    uint32_t r = (u + 0x7fffu + ((u >> 16) & 1u)) >> 16;   // RNE
    return (unsigned short)r;
}
__device__ __forceinline__ float bfhi(uint32_t v) {
    union { uint32_t u; float f; } c; c.u = v & 0xffff0000u; return c.f;
}
__device__ __forceinline__ float bflo(uint32_t v) {
    union { uint32_t u; float f; } c; c.u = v << 16; return c.f;
}

// ------- K0: convert W2 to bf16 (blocks 0..2047) + transpose x to bf16 ----
__global__ __launch_bounds__(256) void k0_prep(
        const float4* __restrict__ W2, ushort4* __restrict__ W2b,
        const float* __restrict__ x, unsigned short* __restrict__ xTb) {
    __shared__ float tile[64][65];
    const int bid = blockIdx.x;
    if (bid < 2048) {
        const int nW2 = (PROJ * IN_DIM * HID) / 4;
        const int stride = 2048 * 256;
        for (int i = bid * 256 + threadIdx.x; i < nW2; i += stride) {
            float4 v = W2[i];
            ushort4 o;
            o.x = f2bf(v.x); o.y = f2bf(v.y); o.z = f2bf(v.z); o.w = f2bf(v.w);
            W2b[i] = o;
        }
    } else {
        const int tb = bid - 2048;
        const int bi = tb & 7, bb = tb >> 3;
        const int i0 = bi * 64, b0 = bb * 64;
        const int t = threadIdx.x;
        const int c = t & 63, r4 = t >> 6;
        #pragma unroll
        for (int rr = 0; rr < 64; rr += 4)
            tile[rr + r4][c] = x[(size_t)(b0 + rr + r4) * IN_DIM + i0 + c];
        __syncthreads();
        #pragma unroll
        for (int rr = 0; rr < 64; rr += 4)
            xTb[(size_t)(i0 + rr + r4) * B_SZ + b0 + c] = f2bf(tile[c][rr + r4]);
    }
}

// ---------------- shared: f32 -> bf16x8 load helper ----------------------
__device__ __forceinline__ bf16x8 ld_cvt8(const float* __restrict__ s) {
    float4 a = *(const float4*)s;
    float4 b = *(const float4*)(s + 4);
    bf16x8 r;
    r[0] = (short)f2bf(a.x); r[1] = (short)f2bf(a.y);
    r[2] = (short)f2bf(a.z); r[3] = (short)f2bf(a.w);
    r[4] = (short)f2bf(b.x); r[5] = (short)f2bf(b.y);
    r[6] = (short)f2bf(b.z); r[7] = (short)f2bf(b.w);
    return r;
}

// ---------------- K1: h = relu(ft @ W1^T + b1), bf16 out -----------------
__global__ __launch_bounds__(256) void k1_hidden(
        const float* __restrict__ ft,
        const float* __restrict__ W1,
        const float* __restrict__ b1,
        unsigned short* __restrict__ hb) {
    const int lane = threadIdx.x & 63;
    const int wv   = threadIdx.x >> 6;
    const int l15  = lane & 15, q = lane >> 4;
    const int b0 = blockIdx.x * 32;
    const int n0 = wv * 64;

    f32x4 acc[2][4];
    const f32x4 z4 = {0.f, 0.f, 0.f, 0.f};
    #pragma unroll
    for (int mt = 0; mt < 2; ++mt)
        #pragma unroll
        for (int nt = 0; nt < 4; ++nt) acc[mt][nt] = z4;

    for (int kq = 0; kq < 16; ++kq) {
        const int koff = kq * 32 + q * 8;
        bf16x8 a[2], bb[4];
        #pragma unroll
        for (int mt = 0; mt < 2; ++mt)
            a[mt] = ld_cvt8(ft + (size_t)(b0 + mt*16 + l15) * IN_DIM + koff);
        #pragma unroll
        for (int nt = 0; nt < 4; ++nt)
            bb[nt] = ld_cvt8(W1 + (size_t)(n0 + nt*16 + l15) * IN_DIM + koff);
        #pragma unroll
        for (int mt = 0; mt < 2; ++mt)
            #pragma unroll
            for (int nt = 0; nt < 4; ++nt)
                acc[mt][nt] = __builtin_amdgcn_mfma_f32_16x16x32_bf16(
                    a[mt], bb[nt], acc[mt][nt], 0, 0, 0);
    }
    #pragma unroll
    for (int nt = 0; nt < 4; ++nt) {
        float bias = b1[n0 + nt*16 + l15];
        #pragma unroll
        for (int mt = 0; mt < 2; ++mt)
            #pragma unroll
            for (int r = 0; r < 4; ++r) {
                float v = acc[mt][nt][r] + bias;
                v = fmaxf(v, 0.f);
                hb[(size_t)(b0 + mt*16 + q*4 + r) * HID + n0 + nt*16 + l15] = f2bf(v);
            }
    }
}

// ---------------- K2: out[b,p] = sum_i x[b,i] * b2[p*512+i] --------------
// Bias term of the fused einsum (verified in R1/R4). k3 does out[] += v.
__global__ __launch_bounds__(256) void k2_bias(
        const float* __restrict__ x,
        const float* __restrict__ b2,
        float* __restrict__ out) {
    const int lane = threadIdx.x & 63;
    const int wv   = threadIdx.x >> 6;
    const int l15  = lane & 15, q = lane >> 4;
    const int b0 = blockIdx.x * 32;
    const int n0 = wv * 32;

    f32x4 acc[2][2];
    const f32x4 z4 = {0.f, 0.f, 0.f, 0.f};
    #pragma unroll
    for (int mt = 0; mt < 2; ++mt)
        #pragma unroll
        for (int nt = 0; nt < 2; ++nt) acc[mt][nt] = z4;

    for (int kq = 0; kq < 16; ++kq) {
        const int koff = kq * 32 + q * 8;
        bf16x8 a[2], bb[2];
        #pragma unroll
        for (int mt = 0; mt < 2; ++mt)
            a[mt] = ld_cvt8(x + (size_t)(b0 + mt*16 + l15) * IN_DIM + koff);
        #pragma unroll
        for (int nt = 0; nt < 2; ++nt)
            bb[nt] = ld_cvt8(b2 + (size_t)(n0 + nt*16 + l15) * IN_DIM + koff);
        #pragma unroll
        for (int mt = 0; mt < 2; ++mt)
            #pragma unroll
            for (int nt = 0; nt < 2; ++nt)
                acc[mt][nt] = __builtin_amdgcn_mfma_f32_16x16x32_bf16(
                    a[mt], bb[nt], acc[mt][nt], 0, 0, 0);
    }
    #pragma unroll
    for (int mt = 0; mt < 2; ++mt)
        #pragma unroll
        for (int nt = 0; nt < 2; ++nt)
            #pragma unroll
            for (int r = 0; r < 4; ++r)
                out[(size_t)(b0 + mt*16 + q*4 + r) * PROJ + n0 + nt*16 + l15]
                    = acc[mt][nt][r];
}

// ---------------- K3: out[b,p] += sum_i x[b,i]*(sum_k h[b,k]*W2[p,i,k]) --
// R4's verified counted-vmcnt skeleton + two changes:
//  (1) mt=4, pp=1 (wave = 64 b-rows, block = 1 p x 256 b): each ds_read
//      B-frag feeds 4 MFMAs (was 2) -> W2 LDS bytes/FLOP halved. afr holds
//      only the current K-half (afr[4][4]=64 VGPR); reloaded at t==15
//      BEFORE the stage so the uniform vmcnt(2) covers it (no drain).
//  (2) W2 tile stored [2 khalf][32 rows][64 k] -> every ds_read_b128 has
//      128B rows, chunks 0..7: the exact pattern R2 measured at ZERO
//      bank conflicts (R4's 256B rows held 4.2e7).
// x tile [32 i][256 b] single-buffered; lifecycle: read during compute(t),
// restaged after barrier-2. vm queue/step: [w2(t) 2, x(t) 4, w2(t+1) 2]
// -> uniform vmcnt(2) at loop top.
__global__ __launch_bounds__(256, 3) void k3_main(
        const unsigned short* __restrict__ W2b,
        const unsigned short* __restrict__ hb,
        const unsigned short* __restrict__ xTb,
        float* __restrict__ out) {
    __shared__ unsigned short w2t[2][2][32 * 64];  // [dbuf][khalf][32r][64k] = 16 KB
    __shared__ unsigned short xt[32 * 256];        // [32 i][256 b] = 16 KB
    const int tid  = threadIdx.x;
    const int lane = tid & 63;
    const int wv   = tid >> 6;
    const int l15  = lane & 15, q = lane >> 4;
    const int pgrp = blockIdx.x & 127;            // stride-128 => same XCD per p
    const int bsup = blockIdx.x >> 7;             // 0..31
    const int p0   = pgrp;
    const int b0blk = bsup * 256;
    const int b0w  = b0blk + wv * 64;             // 64 b-rows per wave
    const f32x4 z4 = {0.f, 0.f, 0.f, 0.f};

    // ---- h fragments for current K-half (kh=0 now; reload at t==15) ----
    bf16x8 afr[4][4];
    #pragma unroll
    for (int mt = 0; mt < 4; ++mt) {
        const unsigned short* hrow = hb + (size_t)(b0w + mt*16 + l15) * HID + q * 8;
        #pragma unroll
        for (int kq = 0; kq < 4; ++kq)
            afr[mt][kq] = *(const bf16x8*)(hrow + kq * 32);
    }

    // ---- glds source pointers (per-lane, pre-swizzled) ----
    // W2: 2 instrs, jj = khalf. Each writes 8 rows x 128B (1KB).
    //   lane -> row_local = wv*8 + (lane>>3), pos = lane&7,
    //   source chunk c = pos ^ (lane>>3)   [row_local&7 == lane>>3]
    const unsigned short* wsp[2];
    #pragma unroll
    for (int jj = 0; jj < 2; ++jj) {
        const int rl = wv*8 + (lane >> 3);
        const int c  = (lane & 7) ^ (lane >> 3);
        wsp[jj] = W2b + ((size_t)p0 * IN_DIM + rl) * HID + jj * 64 + c * 8;
    }
    // x: 4 instrs, each writes 2 rows x 512B (1KB).
    //   lane -> row r = wv*8 + jj*2 + (lane>>5), pos = lane&31 (16B chunks),
    //   source chunk c = pos ^ (r&7)
    const unsigned short* xsp[4];
    #pragma unroll
    for (int jj = 0; jj < 4; ++jj) {
        const int r = wv*8 + jj*2 + (lane >> 5);
        const int c = (lane & 31) ^ (r & 7);
        xsp[jj] = xTb + (size_t)r * B_SZ + b0blk + c * 8;
    }

    float oacc[4][4];
    #pragma unroll
    for (int mt = 0; mt < 4; ++mt)
        #pragma unroll
        for (int r = 0; r < 4; ++r) oacc[mt][r] = 0.f;

#define STAGE_W2(BUFI, TT) do {                                           \
    const int _kh = (TT) >> 4, _ic = (TT) & 15;                           \
    const size_t _add = (size_t)(_ic * 32) * HID + _kh * 128;             \
    _Pragma("unroll")                                                     \
    for (int _jj = 0; _jj < 2; ++_jj)                                     \
        GLDS16(wsp[_jj] + _add, &w2t[BUFI][_jj][wv * 512]);               \
} while (0)

#define STAGE_X(TT) do {                                                  \
    const size_t _add = (size_t)(((TT) & 15) * 32) * B_SZ;                \
    _Pragma("unroll")                                                     \
    for (int _jj = 0; _jj < 4; ++_jj)                                     \
        GLDS16(xsp[_jj] + _add, &xt[(wv*8 + _jj*2) * 256]);               \
} while (0)

#define COMPUTE() do {                                                    \
    _Pragma("unroll")                                                     \
    for (int sub = 0; sub < 2; ++sub) {                                   \
        const int rloc = sub*16 + l15;                                    \
        const int sw   = rloc & 7;                                        \
        uint2 xv[4];                                                      \
        _Pragma("unroll")                                                 \
        for (int mt = 0; mt < 4; ++mt) {                                  \
            const int cc = wv*8 + mt*2 + (q >> 1);                        \
            const int ss = cc ^ sw;                                       \
            xv[mt] = *(const uint2*)(&xt[rloc*256 + ss*8 + (q & 1)*4]);   \
        }                                                                 \
        bf16x8 bfr[4];                                                    \
        _Pragma("unroll")                                                 \
        for (int kq = 0; kq < 4; ++kq) {                                  \
            const int khf = kq >> 1;                                      \
            const int ch  = (q + 4*(kq & 1)) ^ sw;                        \
            bfr[kq] = *(const bf16x8*)(Lw + khf*2048 + rloc*64 + ch*8);   \
        }                                                                 \
        f32x4 D[4];                                                       \
        _Pragma("unroll")                                                 \
        for (int mt = 0; mt < 4; ++mt)                                    \
            D[mt] = __builtin_amdgcn_mfma_f32_16x16x32_bf16(              \
                afr[mt][0], bfr[0], z4, 0, 0, 0);                         \
        _Pragma("unroll")                                                 \
        for (int kq = 1; kq < 4; ++kq)                                    \
            _Pragma("unroll")                                             \
            for (int mt = 0; mt < 4; ++mt)                                \
                D[mt] = __builtin_amdgcn_mfma_f32_16x16x32_bf16(          \
                    afr[mt][kq], bfr[kq], D[mt], 0, 0, 0);                \
        _Pragma("unroll")                                                 \
        for (int mt = 0; mt < 4; ++mt) {                                  \
            oacc[mt][0] = fmaf(D[mt][0], bflo(xv[mt].x), oacc[mt][0]);    \
            oacc[mt][1] = fmaf(D[mt][1], bfhi(xv[mt].x), oacc[mt][1]);    \
            oacc[mt][2] = fmaf(D[mt][2], bflo(xv[mt].y), oacc[mt][2]);    \
            oacc[mt][3] = fmaf(D[mt][3], bfhi(xv[mt].y), oacc[mt][3]);    \
        }                                                                 \
    }                                                                     \
} while (0)

    // ---- prologue: queue = [w2(0) 2, x(0) 4, w2(1) 2] ----
    STAGE_W2(0, 0);
    STAGE_X(0);
    STAGE_W2(1, 1);

    #pragma unroll 1
    for (int t = 0; t < 32; ++t) {
        // need w2(t), x(t) landed; w2(t+1) (2 newest) may stay in flight
        if (t < 31) asm volatile("s_waitcnt vmcnt(2)" ::: "memory");
        else        asm volatile("s_waitcnt vmcnt(0)" ::: "memory");
        __builtin_amdgcn_s_barrier();     // all waves' tile-t data visible
        asm volatile("" ::: "memory");

        const unsigned short* Lw = &w2t[t & 1][0][0];
        COMPUTE();

        asm volatile("" ::: "memory");
        __builtin_amdgcn_s_barrier();     // all waves done reading buffers
        asm volatile("" ::: "memory");

        if (t == 15) {   // reload afr for kh=1; BEFORE stage => older in vm
            #pragma unroll  // queue, so the next vmcnt(2) covers it (no drain)
            for (int mt = 0; mt < 4; ++mt) {
                const unsigned short* hrow =
                    hb + (size_t)(b0w + mt*16 + l15) * HID + 128 + q * 8;
                #pragma unroll
                for (int kq = 0; kq < 4; ++kq)
                    afr[mt][kq] = *(const bf16x8*)(hrow + kq * 32);
            }
        }
        if (t < 31) STAGE_X(t + 1);
        if (t < 30) STAGE_W2(t & 1, t + 2);
    }
#undef STAGE_W2
#undef STAGE_X
#undef COMPUTE

    // ---- epilogue: reduce over 16 i-lanes, accumulate onto k2's bias ----
    #pragma unroll
    for (int mt = 0; mt < 4; ++mt)
        #pragma unroll
        for (int r = 0; r < 4; ++r) {
            float v = oacc[mt][r];
            v += __shfl_xor(v, 1, 16);
            v += __shfl_xor(v, 2, 16);
            v += __shfl_xor(v, 4, 16);
            v += __shfl_xor(v, 8, 16);
            if (l15 == 0)
                out[(size_t)(b0w + mt*16 + q*4 + r) * PROJ + p0] += v;
        }
}

extern "C" void kernel_launch(void* const* d_in, const int* in_sizes, int n_in,
                              void* d_out, int out_size, void* d_ws, size_t ws_size,
                              hipStream_t stream) {
    const float* ft = (const float*)d_in[0];
    const float* x  = (const float*)d_in[1];
    const float* W1 = (const float*)d_in[2];
    const float* b1 = (const float*)d_in[3];
    const float* W2 = (const float*)d_in[4];
    const float* b2 = (const float*)d_in[5];
    float* out = (float*)d_out;

    char* ws = (char*)d_ws;
    unsigned short* W2b = (unsigned short*)(ws);             // 33,554,432 B
    unsigned short* hb  = (unsigned short*)(ws + 33554432);  //  4,194,304 B
    unsigned short* xTb = (unsigned short*)(ws + 37748736);  //  8,388,608 B

    hipLaunchKernelGGL(k0_prep, dim3(3072), dim3(256), 0, stream,
        (const float4*)W2, (ushort4*)W2b, x, xTb);
    hipLaunchKernelGGL(k1_hidden, dim3(256), dim3(256), 0, stream, ft, W1, b1, hb);
    hipLaunchKernelGGL(k2_bias, dim3(256), dim3(256), 0, stream, x, b2, out);
    hipLaunchKernelGGL(k3_main, dim3(4096), dim3(256), 0, stream, W2b, hb, xTb, out);
}